// Round 5
// baseline (679.513 us; speedup 1.0000x reference)
//
#include <hip/hip_runtime.h>

#define N_NODES 131072
#define N_EDGES 524288
#define K_TOP   65536
#define LN_EPS  1e-5f

typedef unsigned int u32;
typedef unsigned short u16;
typedef unsigned long long u64;

typedef __attribute__((ext_vector_type(8))) short bf8;
typedef __attribute__((ext_vector_type(4))) float f4;

// ---- ws layout (requires ws >= 40 MB) ----
#define ST_OFF    0             // SelState (~52KB, reserve 64KB)
#define CANON_OFF (64u<<10)     // canon + transposed weights (~461KB) -> [64K, 576K)
#define PART_OFF  (576u<<10)    // radix partials 256KB; +2KB: gcur[256]
#define KEYS_OFF  (1u<<20)      // keys u64[N] = 1MB; after k_mark reused as DEG u32[N]
#define TVAL_OFF  (2u<<20)      // N f32 = 512KB
#define KEPT_OFF  ((2u<<20)+(512u<<10)) // N u32 = 512KB
#define SBUF_OFF  (3u<<20)      // big buffer: N x 64 u32 = 32MB; pre-proj: pairs[2E] 4MB
#define OFF_OFF   (35u<<20)     // CSR off u32[N+1] = 512KB+4
#define ADJ_OFF   (36u<<20)     // CSR adj u32[2E] = 4MB -> ends 40M

// Big-buffer ping-pong (d_out doubles as scratch):
//   CSR: pairs=ws.SBUF (consumed by k_place before k_proj_down reuses SBUF)
//   down: S=ws.SBUF -> k_agg<1> -> H=d_out -> k_mlp<1> -> R=ws.SBUF
//   up:   k_proj_up(R=ws) -> S2=d_out -> k_agg<0> -> H=ws.SBUF -> k_mlp<0> -> d_out

// canonical parameter block offsets (bf16 elements)
#define C_DW1 0
#define C_DB1 16384
#define C_DW2 16512
#define C_DB2 32896
#define C_DW3 33024
#define C_DB3 49408
#define C_DG  49536
#define C_DBE 49664
#define C_UW1 49792
#define C_UB1 82560
#define C_UW2 82688
#define C_UB2 99072
#define C_UW3 99200
#define C_UB3 115584
#define C_UG  115712
#define C_UBE 115840
#define C_TOT 115968
// transposed weights WT[n][k] appended
#define CT_DW1 115968
#define CT_DW2 132352
#define CT_DW3 148736
#define CT_UW1 165120   /* [128][256] */
#define CT_UW2 197888
#define CT_UW3 214272
#define CT_TOT 230656
#define T_REGION (CT_TOT - CT_DW1)   /* 114688 */

__device__ __forceinline__ float bflo(u32 u){ return __uint_as_float(u << 16); }
__device__ __forceinline__ float bfhi(u32 u){ return __uint_as_float(u & 0xFFFF0000u); }
__device__ __forceinline__ float bf2f(u16 v){ return __uint_as_float(((u32)v) << 16); }
__device__ __forceinline__ u32 f2bf(float f){
  u32 u = __float_as_uint(f);
  return (u + 0x7FFFu + ((u >> 16) & 1u)) >> 16;
}
__device__ __forceinline__ float gelu_f(float x){
  return 0.5f * x * (1.0f + erff(x * 0.7071067811865476f));
}

// wave-level 16x128 GEMM over K=128: A from LDS (own rows), B direct from global
// (L2-hot weights). Hand software-pipelined: 8 B-fragments for K-slice s preloaded
// in named registers; loads for s+1 issued before the MFMAs of s so ~8-16 VMEM ops
// stay in flight per wave (round-4 post-mortem: compiler alone serialized these at
// 48 VGPRs -> L2-latency-bound, MfmaUtil 3.8%).
__device__ __forceinline__ void wave_gemm_g(const u16* in_s, const u16* __restrict__ Wg,
                                            int ldw, int m0, int mn, int quad, f4 acc[8]){
  const u16* __restrict__ wp = Wg + mn * ldw + quad * 8;
  const u16* ap = in_s + (m0 + mn) * 136 + quad * 8;
  bf8 b0, b1, b2, b3, b4, b5, b6, b7;
  b0 = *(const bf8*)(wp + 0 * 16 * ldw); b1 = *(const bf8*)(wp + 1 * 16 * ldw);
  b2 = *(const bf8*)(wp + 2 * 16 * ldw); b3 = *(const bf8*)(wp + 3 * 16 * ldw);
  b4 = *(const bf8*)(wp + 4 * 16 * ldw); b5 = *(const bf8*)(wp + 5 * 16 * ldw);
  b6 = *(const bf8*)(wp + 6 * 16 * ldw); b7 = *(const bf8*)(wp + 7 * 16 * ldw);
  #pragma unroll
  for (int s = 0; s < 4; s++){
    bf8 a = *(const bf8*)(ap + s * 32);
    bf8 n0, n1, n2, n3, n4, n5, n6, n7;
    if (s < 3){
      const u16* __restrict__ wn = wp + (s + 1) * 32;
      n0 = *(const bf8*)(wn + 0 * 16 * ldw); n1 = *(const bf8*)(wn + 1 * 16 * ldw);
      n2 = *(const bf8*)(wn + 2 * 16 * ldw); n3 = *(const bf8*)(wn + 3 * 16 * ldw);
      n4 = *(const bf8*)(wn + 4 * 16 * ldw); n5 = *(const bf8*)(wn + 5 * 16 * ldw);
      n6 = *(const bf8*)(wn + 6 * 16 * ldw); n7 = *(const bf8*)(wn + 7 * 16 * ldw);
    }
    acc[0] = __builtin_amdgcn_mfma_f32_16x16x32_bf16(a, b0, acc[0], 0, 0, 0);
    acc[1] = __builtin_amdgcn_mfma_f32_16x16x32_bf16(a, b1, acc[1], 0, 0, 0);
    acc[2] = __builtin_amdgcn_mfma_f32_16x16x32_bf16(a, b2, acc[2], 0, 0, 0);
    acc[3] = __builtin_amdgcn_mfma_f32_16x16x32_bf16(a, b3, acc[3], 0, 0, 0);
    acc[4] = __builtin_amdgcn_mfma_f32_16x16x32_bf16(a, b4, acc[4], 0, 0, 0);
    acc[5] = __builtin_amdgcn_mfma_f32_16x16x32_bf16(a, b5, acc[5], 0, 0, 0);
    acc[6] = __builtin_amdgcn_mfma_f32_16x16x32_bf16(a, b6, acc[6], 0, 0, 0);
    acc[7] = __builtin_amdgcn_mfma_f32_16x16x32_bf16(a, b7, acc[7], 0, 0, 0);
    if (s < 3){
      b0 = n0; b1 = n1; b2 = n2; b3 = n3;
      b4 = n4; b5 = n5; b6 = n6; b7 = n7;
    }
  }
}

struct SelState {
  u64 prefix;
  u32 krem, eqcnt;
  int is_f32;
  u32 pad;
  double inv_norm;
  u32 eqlist[4096];
  u64 eqkey[4096];
};

struct P16 { const void* q[16]; };

// ---------------- dtype detection ----------------
__global__ void k_detect(const u32* __restrict__ xw, SelState* st){
  int t = threadIdx.x;
  int cnt = 0;
  for (int i = t; i < 4096; i += 256){
    u32 w = xw[(size_t)i * 2048];
    u32 e = (w >> 23) & 0xFFu;
    if (e >= 97u && e <= 135u) cnt++;
  }
  __shared__ int sh[256];
  sh[t] = cnt; __syncthreads();
  for (int o = 128; o > 0; o >>= 1){ if (t < o) sh[t] += sh[t+o]; __syncthreads(); }
  if (t == 0) st->is_f32 = (sh[0] >= 3072) ? 1 : 0;
}

__global__ void k_init(SelState* st){
  if (threadIdx.x == 0){ st->prefix = 0; st->krem = K_TOP; st->eqcnt = 0; }
}

__global__ void k_canon(P16 ps, const SelState* __restrict__ st, u16* __restrict__ canon){
  const int off[17] = {C_DW1,C_DB1,C_DW2,C_DB2,C_DW3,C_DB3,C_DG,C_DBE,
                       C_UW1,C_UB1,C_UW2,C_UB2,C_UW3,C_UB3,C_UG,C_UBE,C_TOT};
  int i = blockIdx.x * 256 + threadIdx.x;
  if (i >= C_TOT) return;
  int seg = 0;
  #pragma unroll
  for (int s2 = 0; s2 < 16; s2++) if (i >= off[s2+1]) seg = s2 + 1;
  int j = i - off[seg];
  if (st->is_f32) canon[i] = (u16)f2bf(((const float*)ps.q[seg])[j]);
  else            canon[i] = ((const u16*)ps.q[seg])[j];
}

// build transposed weights WT[n][k] from canon W[k][n] (N==128 for all)
__global__ void k_canon_t(u16* __restrict__ canon){
  const int src[6] = {C_DW1, C_DW2, C_DW3, C_UW1, C_UW2, C_UW3};
  const int dst[7] = {CT_DW1, CT_DW2, CT_DW3, CT_UW1, CT_UW2, CT_UW3, CT_TOT};
  int i = blockIdx.x * 256 + threadIdx.x;
  if (i >= T_REGION) return;
  int g = CT_DW1 + i;
  int seg = 0;
  #pragma unroll
  for (int s2 = 0; s2 < 6; s2++) if (g >= dst[s2+1]) seg = s2 + 1;
  int loc = g - dst[seg];
  int K = (seg == 3) ? 256 : 128;
  int n = loc / K, k = loc % K;
  canon[g] = canon[src[seg] + k * 128 + n];
}

__global__ void k_pnorm(const void* __restrict__ p, SelState* st){
  int t = threadIdx.x;
  float pv = st->is_f32 ? ((const float*)p)[t] : bf2f(((const u16*)p)[t]);
  __shared__ double sh[128];
  sh[t] = (double)pv * (double)pv;
  __syncthreads();
  for (int o = 64; o > 0; o >>= 1){ if (t < o) sh[t] += sh[t+o]; __syncthreads(); }
  if (t == 0) st->inv_norm = 1.0 / sqrt(sh[0]);
}

__global__ __launch_bounds__(256) void k_score(const void* __restrict__ xraw, const void* __restrict__ praw,
                        const SelState* __restrict__ st,
                        u64* __restrict__ keys, float* __restrict__ tval){
  int t = threadIdx.x, lane = t & 63, w = t >> 6;
  int n = blockIdx.x * 4 + w;
  double d;
  if (st->is_f32){
    const float* xf = (const float*)xraw + (size_t)n * 128;
    const float* pf = (const float*)praw;
    d = (double)xf[lane] * (double)pf[lane]
      + (double)xf[64 + lane] * (double)pf[64 + lane];
  } else {
    const u32* xw = (const u32*)xraw + (size_t)n * 64;
    const u32* pw = (const u32*)praw;
    u32 xx = xw[lane], pv = pw[lane];
    d = (double)bflo(xx) * (double)bflo(pv) + (double)bfhi(xx) * (double)bfhi(pv);
  }
  for (int o = 32; o > 0; o >>= 1) d += __shfl_down(d, o, 64);
  if (lane == 0){
    double sc = d * st->inv_norm;
    u64 u = (u64)__double_as_longlong(sc);
    u64 key = (u & 0x8000000000000000ULL) ? ~u : (u | 0x8000000000000000ULL);
    keys[n] = key;
    tval[n] = tanhf((float)sc);
  }
}

// ---------------- contention-free 4-pass radix select (top 32 bits) ----------------
__global__ __launch_bounds__(256) void k_histp(const u64* __restrict__ keys,
                                               const SelState* __restrict__ st,
                                               u32* __restrict__ partial, int pass){
  __shared__ u32 h[256];
  int t = threadIdx.x;
  h[t] = 0;
  __syncthreads();
  u64 pref = st->prefix;
  int sh_d = 56 - 8 * pass;
  for (int n = blockIdx.x * 256 + t; n < N_NODES; n += 256 * 256){
    u64 k = keys[n];
    bool m = (pass == 0) ? true : ((k >> (sh_d + 8)) == pref);
    if (m) atomicAdd(&h[(u32)((k >> sh_d) & 255)], 1u);
  }
  __syncthreads();
  partial[blockIdx.x * 256 + t] = h[t];
}

__global__ void k_scanp(const u32* __restrict__ partial, SelState* st){
  __shared__ u32 tot[256];
  int t = threadIdx.x;
  u32 s = 0;
  for (int b = 0; b < 256; b++) s += partial[b * 256 + t];
  tot[t] = s;
  __syncthreads();
  if (t == 0){
    u32 target = st->krem;
    u32 cum = 0; int chosen = 255;
    for (int b = 255; b >= 0; b--){
      if (cum + tot[b] >= target){ chosen = b; break; }
      cum += tot[b];
    }
    st->prefix = (st->prefix << 8) | (u64)(u32)chosen;
    st->krem = target - cum;
  }
}

__global__ void k_mark(const u64* __restrict__ keys, SelState* st, u32* __restrict__ kept){
  int n = blockIdx.x * blockDim.x + threadIdx.x;
  u64 k = keys[n];
  u32 t32 = (u32)(k >> 32);
  u32 T = (u32)st->prefix;
  kept[n] = (t32 > T) ? 1u : 0u;
  if (t32 == T){
    u32 i = atomicAdd(&st->eqcnt, 1u);
    if (i < 4096){ st->eqlist[i] = (u32)n; st->eqkey[i] = k; }
  }
}

__global__ void k_tie(SelState* st, u32* __restrict__ kept){
  u32 m = st->eqcnt; if (m > 4096) m = 4096;
  u32 r = st->krem;
  for (u32 i = threadIdx.x; i < m; i += blockDim.x){
    u64 ki = st->eqkey[i]; u32 ii = st->eqlist[i];
    u32 rank = 0;
    for (u32 j = 0; j < m; j++){
      u64 kj = st->eqkey[j];
      rank += (kj > ki || (kj == ki && st->eqlist[j] < ii)) ? 1u : 0u;
    }
    if (rank < r) kept[ii] = 1u;
  }
}

// ---------------- CSR build (symmetrized adjacency), bucketed 2-pass ----------------
__global__ __launch_bounds__(256) void k_deg(const int* __restrict__ se, const int* __restrict__ re,
                                             u32* __restrict__ deg){
  int e = blockIdx.x * 256 + threadIdx.x;
  int s = se[e], r = re[e];
  atomicAdd(&deg[s], 1u);
  atomicAdd(&deg[r], 1u);
}

__global__ __launch_bounds__(256) void k_scan1(const u32* __restrict__ deg, u32* __restrict__ bsum){
  __shared__ u32 sh[256];
  int t = threadIdx.x;
  int base = blockIdx.x * 1024 + t * 4;
  u32 s = deg[base] + deg[base+1] + deg[base+2] + deg[base+3];
  sh[t] = s; __syncthreads();
  for (int o = 128; o > 0; o >>= 1){ if (t < o) sh[t] += sh[t+o]; __syncthreads(); }
  if (t == 0) bsum[blockIdx.x] = sh[0];
}

__global__ void k_scan2(u32* __restrict__ bsum){
  __shared__ u32 sh[128];
  int t = threadIdx.x;            // 128 threads
  u32 v = bsum[t];
  sh[t] = v; __syncthreads();
  for (int o = 1; o < 128; o <<= 1){
    u32 x = (t >= o) ? sh[t-o] : 0u;
    __syncthreads();
    sh[t] += x;
    __syncthreads();
  }
  bsum[t] = sh[t] - v;            // exclusive
}

__global__ __launch_bounds__(256) void k_scan3(const u32* __restrict__ bsum,
                                               const u32* __restrict__ deg, u32* __restrict__ off){
  __shared__ u32 sh[256];
  int t = threadIdx.x;
  int base = blockIdx.x * 1024 + t * 4;
  u32 v0 = deg[base], v1 = deg[base+1], v2 = deg[base+2], v3 = deg[base+3];
  u32 s = v0 + v1 + v2 + v3;
  sh[t] = s; __syncthreads();
  for (int o = 1; o < 256; o <<= 1){
    u32 x = (t >= o) ? sh[t-o] : 0u;
    __syncthreads();
    sh[t] += x;
    __syncthreads();
  }
  u32 ex = sh[t] - s + bsum[blockIdx.x];
  off[base]   = ex; ex += v0;
  off[base+1] = ex; ex += v1;
  off[base+2] = ex; ex += v2;
  off[base+3] = ex;
  if (blockIdx.x == 0 && t == 0) off[N_NODES] = 2u * N_EDGES;
}

// gcur[b] = off[b*512] (start of bucket b's region)
__global__ void k_gcinit(const u32* __restrict__ off, u32* __restrict__ gcur){
  int t = threadIdx.x;
  gcur[t] = off[t * 512];
}

// Pass A: bin (target, neighbor) entries into 256 buckets via LDS, flush coalesced
// into pairs[] laid out at CSR bucket offsets. payload = (nlocal[9b] << 17) | nbr[17b]
__global__ __launch_bounds__(256) void k_bin(const int* __restrict__ se, const int* __restrict__ re,
                                             u32* __restrict__ gcur, u32* __restrict__ pairs){
  __shared__ u32 cnt[256], sc[256], base[256], cur[256], gpos[256];
  __shared__ u32 stage[8192];
  int t = threadIdx.x;
  cnt[t] = 0;
  __syncthreads();
  int e0 = blockIdx.x * 4096;
  for (int i = t; i < 4096; i += 256){
    int s = se[e0 + i], r = re[e0 + i];
    atomicAdd(&cnt[(u32)r >> 9], 1u);
    atomicAdd(&cnt[(u32)s >> 9], 1u);
  }
  __syncthreads();
  sc[t] = cnt[t];
  __syncthreads();
  for (int o = 1; o < 256; o <<= 1){
    u32 x = (t >= o) ? sc[t - o] : 0u;
    __syncthreads();
    sc[t] += x;
    __syncthreads();
  }
  base[t] = sc[t] - cnt[t];
  cur[t] = base[t];
  gpos[t] = atomicAdd(&gcur[t], cnt[t]);
  __syncthreads();
  for (int i = t; i < 4096; i += 256){
    u32 s = (u32)se[e0 + i], r = (u32)re[e0 + i];
    u32 b1 = r >> 9, p1 = ((r & 511u) << 17) | s;
    u32 b2 = s >> 9, p2 = ((s & 511u) << 17) | r;
    stage[atomicAdd(&cur[b1], 1u)] = p1;
    stage[atomicAdd(&cur[b2], 1u)] = p2;
  }
  __syncthreads();
  int lane = t & 63, wv = t >> 6;
  for (int b = wv; b < 256; b += 4){
    u32 n = cnt[b], src = base[b], dst = gpos[b];
    for (u32 i = lane; i < n; i += 64)
      pairs[dst + i] = stage[src + i];
  }
}

// Pass B: one block per bucket; place entries into exact CSR slots. adj writes
// stay inside the bucket's ~16KB window -> L2-combined, no line bouncing.
__global__ __launch_bounds__(256) void k_place(const u32* __restrict__ off,
                                               const u32* __restrict__ pairs,
                                               u32* __restrict__ adj){
  __shared__ u32 offl[513];
  __shared__ u32 curl[512];
  int b = blockIdx.x, t = threadIdx.x;
  for (int i = t; i < 513; i += 256) offl[i] = off[b * 512 + i];
  for (int i = t; i < 512; i += 256) curl[i] = 0;
  __syncthreads();
  u32 beg = offl[0], end = offl[512];
  for (u32 i = beg + t; i < end; i += 256){
    u32 p = pairs[i];
    u32 nl = p >> 17, m = p & 0x1FFFFu;
    u32 slot = offl[nl] + atomicAdd(&curl[nl], 1u);
    adj[slot] = m;
  }
}

// ---------------- MFMA projection GEMMs (wave-private rows, light barriers) ----------------
// S[n] = kept[n] ? bf16(x[n]*tval[n] @ dW1) : 0
__global__ __launch_bounds__(256, 4) void k_proj_down(
    const void* __restrict__ xraw, const float* __restrict__ tval,
    const u16* __restrict__ W1T, const SelState* __restrict__ st,
    const u32* __restrict__ kept, u32* __restrict__ S)
{
  __shared__ u16 in_s[64 * 136];
  int t = threadIdx.x, lane = t & 63, wv = t >> 6;
  int row0 = blockIdx.x * 64;
  int m0 = wv * 16, mn = lane & 15, quad = lane >> 4;
  int r = m0 + (lane >> 2), qt = lane & 3;
  u32* dst = (u32*)&in_s[r * 136 + 2 * (qt * 16)];

  float tv = tval[row0 + r];
  if (st->is_f32){
    const float* xf = (const float*)xraw + (size_t)(row0 + r) * 128 + qt * 32;
    #pragma unroll
    for (int i = 0; i < 16; i++){
      float2 v = *(const float2*)(xf + 2 * i);
      dst[i] = f2bf(v.x * tv) | (f2bf(v.y * tv) << 16);
    }
  } else {
    const u32* xw = (const u32*)xraw + (size_t)(row0 + r) * 64 + qt * 16;
    #pragma unroll
    for (int i = 0; i < 16; i++){
      u32 u = xw[i];
      dst[i] = f2bf(bflo(u) * tv) | (f2bf(bfhi(u) * tv) << 16);
    }
  }
  __syncthreads();   // cross-lane: stage -> gemm reads

  f4 acc[8];
  #pragma unroll
  for (int j = 0; j < 8; j++){ acc[j][0]=0.f; acc[j][1]=0.f; acc[j][2]=0.f; acc[j][3]=0.f; }
  wave_gemm_g(in_s, W1T, 128, m0, mn, quad, acc);
  __syncthreads();   // gemm reads done before repack overwrites

  #pragma unroll
  for (int j = 0; j < 8; j++){
    int c = j * 16 + mn;
    #pragma unroll
    for (int rg = 0; rg < 4; rg++)
      in_s[(m0 + quad * 4 + rg) * 136 + c] = (u16)f2bf(acc[j][rg]);
  }
  __syncthreads();   // repack -> readback

  u32 kp = kept[row0 + r];
  u32* out = S + (size_t)(row0 + r) * 64 + qt * 16;
  #pragma unroll
  for (int i = 0; i < 4; i++){
    uint4 w = *(const uint4*)(dst + 4 * i);
    if (!kp){ w.x = 0; w.y = 0; w.z = 0; w.w = 0; }
    *(uint4*)(out + 4 * i) = w;
  }
}

// S2[n] = bf16(R[n] @ uW1[0:128,:] + x[n] @ uW1[128:256,:])
__global__ __launch_bounds__(256, 4) void k_proj_up(
    const u32* __restrict__ R, const void* __restrict__ xraw,
    const u16* __restrict__ W1T, const SelState* __restrict__ st,
    u32* __restrict__ S2)
{
  __shared__ u16 in_s[64 * 136];
  int t = threadIdx.x, lane = t & 63, wv = t >> 6;
  int row0 = blockIdx.x * 64;
  int m0 = wv * 16, mn = lane & 15, quad = lane >> 4;
  int r = m0 + (lane >> 2), qt = lane & 3;
  u32* dst = (u32*)&in_s[r * 136 + 2 * (qt * 16)];

  f4 acc[8];
  #pragma unroll
  for (int j = 0; j < 8; j++){ acc[j][0]=0.f; acc[j][1]=0.f; acc[j][2]=0.f; acc[j][3]=0.f; }

  // phase 0: A = R rows, B = uW1 rows [0:128)
  {
    const u32* src = R + (size_t)(row0 + r) * 64 + qt * 16;
    #pragma unroll
    for (int i = 0; i < 4; i++){
      uint4 v = *(const uint4*)(src + 4 * i);
      *(uint4*)(dst + 4 * i) = v;
    }
  }
  __syncthreads();
  wave_gemm_g(in_s, W1T, 256, m0, mn, quad, acc);
  __syncthreads();   // gemm0 reads done before stage1 overwrites

  // phase 1: A = x rows, B = uW1 rows [128:256)
  if (st->is_f32){
    const float* xf = (const float*)xraw + (size_t)(row0 + r) * 128 + qt * 32;
    #pragma unroll
    for (int i = 0; i < 16; i++){
      float2 v = *(const float2*)(xf + 2 * i);
      dst[i] = f2bf(v.x) | (f2bf(v.y) << 16);
    }
  } else {
    const u32* xw = (const u32*)xraw + (size_t)(row0 + r) * 64 + qt * 16;
    #pragma unroll
    for (int i = 0; i < 4; i++){
      uint4 v = *(const uint4*)(xw + 4 * i);
      *(uint4*)(dst + 4 * i) = v;
    }
  }
  __syncthreads();
  wave_gemm_g(in_s, W1T + 128, 256, m0, mn, quad, acc);
  __syncthreads();   // gemm1 reads done before repack overwrites

  #pragma unroll
  for (int j = 0; j < 8; j++){
    int c = j * 16 + mn;
    #pragma unroll
    for (int rg = 0; rg < 4; rg++)
      in_s[(m0 + quad * 4 + rg) * 136 + c] = (u16)f2bf(acc[j][rg]);
  }
  __syncthreads();   // repack -> readback

  u32* out = S2 + (size_t)(row0 + r) * 64 + qt * 16;
  #pragma unroll
  for (int i = 0; i < 4; i++)
    *(uint4*)(out + 4 * i) = *(const uint4*)(dst + 4 * i);
}

// ---------------- dedicated high-occupancy pull-aggregation ----------------
template<int IS_DOWN>
__global__ __launch_bounds__(256, 4) void k_agg(
    const u32* __restrict__ Smsg, const u32* __restrict__ off, const u32* __restrict__ adj,
    const u16* __restrict__ cb1, const u32* __restrict__ kept,
    u32* __restrict__ H)
{
  int t = threadIdx.x, lane = t & 63, wv = t >> 6;
  float b1l = bf2f(cb1[2 * lane]), b1h = bf2f(cb1[2 * lane + 1]);
  int base = blockIdx.x * 16 + wv * 4;
  #pragma unroll 1
  for (int rr = 0; rr < 4; rr++){
    int n = base + rr;
    if (IS_DOWN && !kept[n]){ H[(size_t)n * 64 + lane] = 0u; continue; }
    u32 jb = off[n], je = off[n + 1];
    float a0 = 0.f, a1 = 0.f;
    u32 j = jb;
    for (; j + 8 <= je; j += 8){
      u32 e0 = adj[j],   e1 = adj[j+1], e2 = adj[j+2], e3 = adj[j+3];
      u32 e4 = adj[j+4], e5 = adj[j+5], e6 = adj[j+6], e7 = adj[j+7];
      u32 w0 = Smsg[(size_t)e0 * 64 + lane];
      u32 w1 = Smsg[(size_t)e1 * 64 + lane];
      u32 w2 = Smsg[(size_t)e2 * 64 + lane];
      u32 w3 = Smsg[(size_t)e3 * 64 + lane];
      u32 w4 = Smsg[(size_t)e4 * 64 + lane];
      u32 w5 = Smsg[(size_t)e5 * 64 + lane];
      u32 w6 = Smsg[(size_t)e6 * 64 + lane];
      u32 w7 = Smsg[(size_t)e7 * 64 + lane];
      a0 += ((bflo(w0) + bflo(w1)) + (bflo(w2) + bflo(w3)))
          + ((bflo(w4) + bflo(w5)) + (bflo(w6) + bflo(w7)));
      a1 += ((bfhi(w0) + bfhi(w1)) + (bfhi(w2) + bfhi(w3)))
          + ((bfhi(w4) + bfhi(w5)) + (bfhi(w6) + bfhi(w7)));
    }
    for (; j + 4 <= je; j += 4){
      u32 e0 = adj[j], e1 = adj[j+1], e2 = adj[j+2], e3 = adj[j+3];
      u32 w0 = Smsg[(size_t)e0 * 64 + lane];
      u32 w1 = Smsg[(size_t)e1 * 64 + lane];
      u32 w2 = Smsg[(size_t)e2 * 64 + lane];
      u32 w3 = Smsg[(size_t)e3 * 64 + lane];
      a0 += (bflo(w0) + bflo(w1)) + (bflo(w2) + bflo(w3));
      a1 += (bfhi(w0) + bfhi(w1)) + (bfhi(w2) + bfhi(w3));
    }
    for (; j < je; j++){
      u32 w = Smsg[(size_t)adj[j] * 64 + lane];
      a0 += bflo(w); a1 += bfhi(w);
    }
    H[(size_t)n * 64 + lane] = f2bf(gelu_f(a0 + b1l)) | (f2bf(gelu_f(a1 + b1h)) << 16);
  }
}

// ---------------- MFMA MLP tail (no weight staging, in-register LN) ----------------
template<int IS_DOWN>
__global__ __launch_bounds__(256, 4) void k_mlp(
    const u32* __restrict__ H,
    const u16* __restrict__ cW2T, const u16* __restrict__ cb2,
    const u16* __restrict__ cW3T, const u16* __restrict__ cb3,
    const u16* __restrict__ cg, const u16* __restrict__ cbe,
    const u32* __restrict__ kept, const SelState* __restrict__ st,
    u32* __restrict__ Rout, void* __restrict__ fout)
{
  __shared__ u16 in_s[64 * 136];
  int t = threadIdx.x, lane = t & 63, wv = t >> 6;
  int row0 = blockIdx.x * 64;
  int m0 = wv * 16, mn = lane & 15, quad = lane >> 4;
  int r = m0 + (lane >> 2), qt = lane & 3;
  u32* dst = (u32*)&in_s[r * 136 + 2 * (qt * 16)];

  // stage h1 (gelu already applied in k_agg)
  {
    const u32* src = H + (size_t)(row0 + r) * 64 + qt * 16;
    #pragma unroll
    for (int i = 0; i < 4; i++){
      uint4 v = *(const uint4*)(src + 4 * i);
      *(uint4*)(dst + 4 * i) = v;
    }
  }
  __syncthreads();   // stage -> gemm1 reads

  f4 acc[8];
  #pragma unroll
  for (int j = 0; j < 8; j++){ acc[j][0]=0.f; acc[j][1]=0.f; acc[j][2]=0.f; acc[j][3]=0.f; }
  wave_gemm_g(in_s, cW2T, 128, m0, mn, quad, acc);
  __syncthreads();   // gemm1 reads done before h2 repack

  // h2 = gelu(acc + b2) -> own rows
  #pragma unroll
  for (int j = 0; j < 8; j++){
    int c = j * 16 + mn;
    float bb = bf2f(cb2[c]);
    #pragma unroll
    for (int rg = 0; rg < 4; rg++)
      in_s[(m0 + quad * 4 + rg) * 136 + c] = (u16)f2bf(gelu_f(acc[j][rg] + bb));
  }
  __syncthreads();   // h2 repack -> gemm2 reads

  #pragma unroll
  for (int j = 0; j < 8; j++){ acc[j][0]=0.f; acc[j][1]=0.f; acc[j][2]=0.f; acc[j][3]=0.f; }
  wave_gemm_g(in_s, cW3T, 128, m0, mn, quad, acc);

  // y = acc + b3, then in-register LN (16-lane xor tree within quad group:
  // lanes quad*16+mn hold rows m0+quad*4+rg, cols j*16+mn)
  #pragma unroll
  for (int j = 0; j < 8; j++){
    float bb = bf2f(cb3[j * 16 + mn]);
    #pragma unroll
    for (int rg = 0; rg < 4; rg++) acc[j][rg] += bb;
  }
  float s1[4] = {0.f,0.f,0.f,0.f}, s2[4] = {0.f,0.f,0.f,0.f};
  #pragma unroll
  for (int j = 0; j < 8; j++){
    #pragma unroll
    for (int rg = 0; rg < 4; rg++){
      float v = acc[j][rg];
      s1[rg] += v; s2[rg] += v * v;
    }
  }
  #pragma unroll
  for (int o = 1; o < 16; o <<= 1){
    #pragma unroll
    for (int rg = 0; rg < 4; rg++){
      s1[rg] += __shfl_xor(s1[rg], o, 64);
      s2[rg] += __shfl_xor(s2[rg], o, 64);
    }
  }
  float mu[4], rs[4];
  #pragma unroll
  for (int rg = 0; rg < 4; rg++){
    mu[rg] = s1[rg] * 0.0078125f;
    float var = s2[rg] * 0.0078125f - mu[rg] * mu[rg];
    rs[rg] = rsqrtf(var + LN_EPS);
  }
  #pragma unroll
  for (int j = 0; j < 8; j++){
    int c = j * 16 + mn;
    float gg = bf2f(cg[c]), be = bf2f(cbe[c]);
    #pragma unroll
    for (int rg = 0; rg < 4; rg++)
      acc[j][rg] = (acc[j][rg] - mu[rg]) * rs[rg] * gg + be;
  }

  if (!IS_DOWN && st->is_f32){
    // f32 output: direct stores (16 lanes x 4B = 64B contiguous per (j,rg))
    float* fo = (float*)fout;
    #pragma unroll
    for (int j = 0; j < 8; j++){
      #pragma unroll
      for (int rg = 0; rg < 4; rg++)
        fo[(size_t)(row0 + m0 + quad * 4 + rg) * 128 + j * 16 + mn] = acc[j][rg];
    }
    return;   // uniform branch (st->is_f32 grid-uniform): no divergent-barrier issue
  }

  // bf16 output: repack own rows, write coalesced
  __syncthreads();   // gemm2 reads done before final repack
  #pragma unroll
  for (int j = 0; j < 8; j++){
    int c = j * 16 + mn;
    #pragma unroll
    for (int rg = 0; rg < 4; rg++)
      in_s[(m0 + quad * 4 + rg) * 136 + c] = (u16)f2bf(acc[j][rg]);
  }
  __syncthreads();   // repack -> readback

  u32* out = (IS_DOWN ? Rout : (u32*)fout) + (size_t)(row0 + r) * 64 + qt * 16;
  u32 kp = IS_DOWN ? kept[row0 + r] : 1u;
  #pragma unroll
  for (int i = 0; i < 4; i++){
    uint4 w = *(const uint4*)(dst + 4 * i);
    if (!kp){ w.x = 0; w.y = 0; w.z = 0; w.w = 0; }
    *(uint4*)(out + 4 * i) = w;
  }
}

// ---------------- host launch ----------------

extern "C" void kernel_launch(void* const* d_in, const int* in_sizes, int n_in,
                              void* d_out, int out_size, void* d_ws, size_t ws_size,
                              hipStream_t stream)
{
  const void* x     = d_in[0];
  const int* eidx   = (const int*)d_in[1];
  const void* poolp = d_in[2];
  const int* senders = eidx;
  const int* receivers = eidx + N_EDGES;

  char* ws = (char*)d_ws;
  SelState* st = (SelState*)(ws + ST_OFF);
  u16*  canon  = (u16*) (ws + CANON_OFF);
  u32*  partial= (u32*) (ws + PART_OFF);   // radix partials; bsum overlays
  u64*  keys   = (u64*) (ws + KEYS_OFF);
  float* tval  = (float*)(ws + TVAL_OFF);
  u32*  kept   = (u32*) (ws + KEPT_OFF);
  u32*  Sbuf   = (u32*) (ws + SBUF_OFF);   // 32MB ws big-buffer (pairs, then messages)
  u32*  off    = (u32*) (ws + OFF_OFF);
  u32*  adj    = (u32*) (ws + ADJ_OFF);
  u32*  deg    = (u32*) (ws + KEYS_OFF);   // deg overlays keys (dead after k_mark)
  u32*  bsum   = partial;
  u32*  gcur   = partial + 512;            // 256 u32 bucket cursors
  u32*  pairs  = Sbuf;                     // 4MB staging (consumed before proj)
  u32*  Dbuf   = (u32*) d_out;             // 32MB d_out scratch region

  P16 ps;
  for (int i = 0; i < 16; i++) ps.q[i] = d_in[3 + i];

  k_detect<<<1, 256, 0, stream>>>((const u32*)x, st);
  k_init<<<1, 64, 0, stream>>>(st);
  k_canon<<<(C_TOT + 255) / 256, 256, 0, stream>>>(ps, st, canon);
  k_canon_t<<<(T_REGION + 255) / 256, 256, 0, stream>>>(canon);
  k_pnorm<<<1, 128, 0, stream>>>(poolp, st);
  k_score<<<N_NODES / 4, 256, 0, stream>>>(x, poolp, st, keys, tval);
  for (int pass = 0; pass < 4; pass++){
    k_histp<<<256, 256, 0, stream>>>(keys, st, partial, pass);
    k_scanp<<<1, 256, 0, stream>>>(partial, st);
  }
  k_mark<<<N_NODES / 256, 256, 0, stream>>>(keys, st, kept);
  k_tie<<<1, 256, 0, stream>>>(st, kept);

  // ---- CSR build (keys region is dead now): deg -> scan -> bucketed 2-pass fill ----
  hipMemsetAsync(deg, 0, (size_t)N_NODES * 4, stream);
  k_deg<<<N_EDGES / 256, 256, 0, stream>>>(senders, receivers, deg);
  k_scan1<<<128, 256, 0, stream>>>(deg, bsum);
  k_scan2<<<1, 128, 0, stream>>>(bsum);
  k_scan3<<<128, 256, 0, stream>>>(bsum, deg, off);
  k_gcinit<<<1, 256, 0, stream>>>(off, gcur);
  k_bin<<<N_EDGES / 4096, 256, 0, stream>>>(senders, receivers, gcur, pairs);
  k_place<<<256, 256, 0, stream>>>(off, pairs, adj);

  // ---- down conv: S(ws) -> agg H(d_out) -> MLP -> R(ws) ----
  k_proj_down<<<N_NODES / 64, 256, 0, stream>>>(x, tval, canon + CT_DW1, st, kept, Sbuf);
  k_agg<1><<<N_NODES / 16, 256, 0, stream>>>(Sbuf, off, adj, canon + C_DB1, kept, Dbuf);
  k_mlp<1><<<N_NODES / 64, 256, 0, stream>>>(Dbuf,
      canon + CT_DW2, canon + C_DB2, canon + CT_DW3, canon + C_DB3,
      canon + C_DG, canon + C_DBE, kept, st, Sbuf, nullptr);

  // ---- up conv: R(ws) -> S2(d_out) -> agg H(ws) -> MLP -> d_out ----
  k_proj_up<<<N_NODES / 64, 256, 0, stream>>>(Sbuf, x, canon + CT_UW1, st, Dbuf);
  k_agg<0><<<N_NODES / 16, 256, 0, stream>>>(Dbuf, off, adj, canon + C_UB1, kept, Sbuf);
  k_mlp<0><<<N_NODES / 64, 256, 0, stream>>>(Sbuf,
      canon + CT_UW2, canon + C_UB2, canon + CT_UW3, canon + C_UB3,
      canon + C_UG, canon + C_UBE, kept, st, nullptr, d_out);
}

// Round 6
// 525.140 us; speedup vs baseline: 1.2940x; 1.2940x over previous
//
#include <hip/hip_runtime.h>

#define N_NODES 131072
#define N_EDGES 524288
#define K_TOP   65536
#define LN_EPS  1e-5f
#define N_TILES (N_NODES / 64)

typedef unsigned int u32;
typedef unsigned short u16;
typedef unsigned long long u64;

typedef __attribute__((ext_vector_type(8))) short bf8;
typedef __attribute__((ext_vector_type(4))) float f4;

// ---- ws layout (requires ws >= 40 MB) ----
#define ST_OFF    0             // SelState (~52KB, reserve 64KB)
#define CANON_OFF (64u<<10)     // canon + transposed weights (~461KB) -> [64K, 576K)
#define PART_OFF  (576u<<10)    // radix partials 256KB; +2KB: gcur[256]
#define KEYS_OFF  (1u<<20)      // keys u64[N] = 1MB; after k_mark reused as DEG u32[N]
#define TVAL_OFF  (2u<<20)      // N f32 = 512KB
#define KEPT_OFF  ((2u<<20)+(512u<<10)) // N u32 = 512KB
#define SBUF_OFF  (3u<<20)      // big buffer: N x 64 u32 = 32MB; pre-proj: pairs[2E] 4MB
#define OFF_OFF   (35u<<20)     // CSR off u32[N+1] = 512KB+4
#define ADJ_OFF   (36u<<20)     // CSR adj u32[2E] = 4MB -> ends 40M

// Big-buffer ping-pong (d_out doubles as scratch):
//   CSR: pairs=ws.SBUF (consumed by k_place before k_proj_down reuses SBUF)
//   down: S=ws.SBUF -> k_agg<1> -> H=d_out -> k_mlp<1> -> R=ws.SBUF
//   up:   k_proj_up(R=ws) -> S2=d_out -> k_agg<0> -> H=ws.SBUF -> k_mlp<0> -> d_out

// canonical parameter block offsets (bf16 elements)
#define C_DW1 0
#define C_DB1 16384
#define C_DW2 16512
#define C_DB2 32896
#define C_DW3 33024
#define C_DB3 49408
#define C_DG  49536
#define C_DBE 49664
#define C_UW1 49792
#define C_UB1 82560
#define C_UW2 82688
#define C_UB2 99072
#define C_UW3 99200
#define C_UB3 115584
#define C_UG  115712
#define C_UBE 115840
#define C_TOT 115968
// transposed weights WT[n][k] appended
#define CT_DW1 115968
#define CT_DW2 132352
#define CT_DW3 148736
#define CT_UW1 165120   /* [128][256] */
#define CT_UW2 197888
#define CT_UW3 214272
#define CT_TOT 230656
#define T_REGION (CT_TOT - CT_DW1)   /* 114688 */

__device__ __forceinline__ float bflo(u32 u){ return __uint_as_float(u << 16); }
__device__ __forceinline__ float bfhi(u32 u){ return __uint_as_float(u & 0xFFFF0000u); }
__device__ __forceinline__ float bf2f(u16 v){ return __uint_as_float(((u32)v) << 16); }
__device__ __forceinline__ u32 f2bf(float f){
  u32 u = __float_as_uint(f);
  return (u + 0x7FFFu + ((u >> 16) & 1u)) >> 16;
}
__device__ __forceinline__ float gelu_f(float x){
  return 0.5f * x * (1.0f + erff(x * 0.7071067811865476f));
}

// ---- swizzled LDS layout for [128 or 64 rows][16 chunks of 16B] matrices ----
// u16 index of chunk cc (0..15) of row: XOR-swizzle kills the 256B-stride bank
// pathology (16 lanes reading same chunk col of consecutive rows spread over banks).
__device__ __forceinline__ int swz16(int row, int cc){
  return row * 128 + ((cc ^ (row & 15)) * 8);
}

// A-fragment chunk builders (fragment lives in VGPRs; chunk cc = s*4+quad)
__device__ __forceinline__ bf8 ld_bf16_chunk(const u32* __restrict__ rowp, int s, int quad){
  uint4 v = *(const uint4*)(rowp + s * 16 + quad * 4);
  return __builtin_bit_cast(bf8, v);
}
__device__ __forceinline__ bf8 scale_bf16_chunk(const u32* __restrict__ rowp, int s, int quad, float tv){
  uint4 v = *(const uint4*)(rowp + s * 16 + quad * 4);
  uint4 q;
  q.x = f2bf(bflo(v.x) * tv) | (f2bf(bfhi(v.x) * tv) << 16);
  q.y = f2bf(bflo(v.y) * tv) | (f2bf(bfhi(v.y) * tv) << 16);
  q.z = f2bf(bflo(v.z) * tv) | (f2bf(bfhi(v.z) * tv) << 16);
  q.w = f2bf(bflo(v.w) * tv) | (f2bf(bfhi(v.w) * tv) << 16);
  return __builtin_bit_cast(bf8, q);
}
__device__ __forceinline__ bf8 cvt_f32_chunk(const float* __restrict__ rowp, int s, int quad, float tv){
  const float* p = rowp + s * 32 + quad * 8;
  float4 f0 = *(const float4*)p;
  float4 f1 = *(const float4*)(p + 4);
  uint4 q;
  q.x = f2bf(f0.x * tv) | (f2bf(f0.y * tv) << 16);
  q.y = f2bf(f0.z * tv) | (f2bf(f0.w * tv) << 16);
  q.z = f2bf(f1.x * tv) | (f2bf(f1.y * tv) << 16);
  q.w = f2bf(f1.z * tv) | (f2bf(f1.w * tv) << 16);
  return __builtin_bit_cast(bf8, q);
}

// 16x128 @ 128x128 GEMM step: A fragments in regs, B in swizzled LDS.
__device__ __forceinline__ void gemm_ab(const u16* ws, const bf8 a[4], int mn, int quad, f4 acc[8]){
  #pragma unroll
  for (int s = 0; s < 4; s++){
    #pragma unroll
    for (int j = 0; j < 8; j++){
      bf8 b = *(const bf8*)&ws[swz16(j * 16 + mn, s * 4 + quad)];
      acc[j] = __builtin_amdgcn_mfma_f32_16x16x32_bf16(a[s], b, acc[j], 0, 0, 0);
    }
  }
}

struct SelState {
  u64 prefix;
  u32 krem, eqcnt;
  int is_f32;
  u32 pad;
  double inv_norm;
  u32 eqlist[4096];
  u64 eqkey[4096];
};

struct P16 { const void* q[16]; };

// ---------------- dtype detection ----------------
__global__ void k_detect(const u32* __restrict__ xw, SelState* st){
  int t = threadIdx.x;
  int cnt = 0;
  for (int i = t; i < 4096; i += 256){
    u32 w = xw[(size_t)i * 2048];
    u32 e = (w >> 23) & 0xFFu;
    if (e >= 97u && e <= 135u) cnt++;
  }
  __shared__ int sh[256];
  sh[t] = cnt; __syncthreads();
  for (int o = 128; o > 0; o >>= 1){ if (t < o) sh[t] += sh[t+o]; __syncthreads(); }
  if (t == 0) st->is_f32 = (sh[0] >= 3072) ? 1 : 0;
}

__global__ void k_init(SelState* st){
  if (threadIdx.x == 0){ st->prefix = 0; st->krem = K_TOP; st->eqcnt = 0; }
}

__global__ void k_canon(P16 ps, const SelState* __restrict__ st, u16* __restrict__ canon){
  const int off[17] = {C_DW1,C_DB1,C_DW2,C_DB2,C_DW3,C_DB3,C_DG,C_DBE,
                       C_UW1,C_UB1,C_UW2,C_UB2,C_UW3,C_UB3,C_UG,C_UBE,C_TOT};
  int i = blockIdx.x * 256 + threadIdx.x;
  if (i >= C_TOT) return;
  int seg = 0;
  #pragma unroll
  for (int s2 = 0; s2 < 16; s2++) if (i >= off[s2+1]) seg = s2 + 1;
  int j = i - off[seg];
  if (st->is_f32) canon[i] = (u16)f2bf(((const float*)ps.q[seg])[j]);
  else            canon[i] = ((const u16*)ps.q[seg])[j];
}

// build transposed weights WT[n][k] from canon W[k][n] (N==128 for all)
__global__ void k_canon_t(u16* __restrict__ canon){
  const int src[6] = {C_DW1, C_DW2, C_DW3, C_UW1, C_UW2, C_UW3};
  const int dst[7] = {CT_DW1, CT_DW2, CT_DW3, CT_UW1, CT_UW2, CT_UW3, CT_TOT};
  int i = blockIdx.x * 256 + threadIdx.x;
  if (i >= T_REGION) return;
  int g = CT_DW1 + i;
  int seg = 0;
  #pragma unroll
  for (int s2 = 0; s2 < 6; s2++) if (g >= dst[s2+1]) seg = s2 + 1;
  int loc = g - dst[seg];
  int K = (seg == 3) ? 256 : 128;
  int n = loc / K, k = loc % K;
  canon[g] = canon[src[seg] + k * 128 + n];
}

__global__ void k_pnorm(const void* __restrict__ p, SelState* st){
  int t = threadIdx.x;
  float pv = st->is_f32 ? ((const float*)p)[t] : bf2f(((const u16*)p)[t]);
  __shared__ double sh[128];
  sh[t] = (double)pv * (double)pv;
  __syncthreads();
  for (int o = 64; o > 0; o >>= 1){ if (t < o) sh[t] += sh[t+o]; __syncthreads(); }
  if (t == 0) st->inv_norm = 1.0 / sqrt(sh[0]);
}

__global__ __launch_bounds__(256) void k_score(const void* __restrict__ xraw, const void* __restrict__ praw,
                        const SelState* __restrict__ st,
                        u64* __restrict__ keys, float* __restrict__ tval){
  int t = threadIdx.x, lane = t & 63, w = t >> 6;
  int n = blockIdx.x * 4 + w;
  double d;
  if (st->is_f32){
    const float* xf = (const float*)xraw + (size_t)n * 128;
    const float* pf = (const float*)praw;
    d = (double)xf[lane] * (double)pf[lane]
      + (double)xf[64 + lane] * (double)pf[64 + lane];
  } else {
    const u32* xw = (const u32*)xraw + (size_t)n * 64;
    const u32* pw = (const u32*)praw;
    u32 xx = xw[lane], pv = pw[lane];
    d = (double)bflo(xx) * (double)bflo(pv) + (double)bfhi(xx) * (double)bfhi(pv);
  }
  for (int o = 32; o > 0; o >>= 1) d += __shfl_down(d, o, 64);
  if (lane == 0){
    double sc = d * st->inv_norm;
    u64 u = (u64)__double_as_longlong(sc);
    u64 key = (u & 0x8000000000000000ULL) ? ~u : (u | 0x8000000000000000ULL);
    keys[n] = key;
    tval[n] = tanhf((float)sc);
  }
}

// ---------------- contention-free 4-pass radix select (top 32 bits) ----------------
__global__ __launch_bounds__(256) void k_histp(const u64* __restrict__ keys,
                                               const SelState* __restrict__ st,
                                               u32* __restrict__ partial, int pass){
  __shared__ u32 h[256];
  int t = threadIdx.x;
  h[t] = 0;
  __syncthreads();
  u64 pref = st->prefix;
  int sh_d = 56 - 8 * pass;
  for (int n = blockIdx.x * 256 + t; n < N_NODES; n += 256 * 256){
    u64 k = keys[n];
    bool m = (pass == 0) ? true : ((k >> (sh_d + 8)) == pref);
    if (m) atomicAdd(&h[(u32)((k >> sh_d) & 255)], 1u);
  }
  __syncthreads();
  partial[blockIdx.x * 256 + t] = h[t];
}

__global__ void k_scanp(const u32* __restrict__ partial, SelState* st){
  __shared__ u32 tot[256];
  int t = threadIdx.x;
  u32 s = 0;
  for (int b = 0; b < 256; b++) s += partial[b * 256 + t];
  tot[t] = s;
  __syncthreads();
  if (t == 0){
    u32 target = st->krem;
    u32 cum = 0; int chosen = 255;
    for (int b = 255; b >= 0; b--){
      if (cum + tot[b] >= target){ chosen = b; break; }
      cum += tot[b];
    }
    st->prefix = (st->prefix << 8) | (u64)(u32)chosen;
    st->krem = target - cum;
  }
}

__global__ void k_mark(const u64* __restrict__ keys, SelState* st, u32* __restrict__ kept){
  int n = blockIdx.x * blockDim.x + threadIdx.x;
  u64 k = keys[n];
  u32 t32 = (u32)(k >> 32);
  u32 T = (u32)st->prefix;
  kept[n] = (t32 > T) ? 1u : 0u;
  if (t32 == T){
    u32 i = atomicAdd(&st->eqcnt, 1u);
    if (i < 4096){ st->eqlist[i] = (u32)n; st->eqkey[i] = k; }
  }
}

__global__ void k_tie(SelState* st, u32* __restrict__ kept){
  u32 m = st->eqcnt; if (m > 4096) m = 4096;
  u32 r = st->krem;
  for (u32 i = threadIdx.x; i < m; i += blockDim.x){
    u64 ki = st->eqkey[i]; u32 ii = st->eqlist[i];
    u32 rank = 0;
    for (u32 j = 0; j < m; j++){
      u64 kj = st->eqkey[j];
      rank += (kj > ki || (kj == ki && st->eqlist[j] < ii)) ? 1u : 0u;
    }
    if (rank < r) kept[ii] = 1u;
  }
}

// ---------------- CSR build (symmetrized adjacency), bucketed 2-pass ----------------
__global__ __launch_bounds__(256) void k_deg(const int* __restrict__ se, const int* __restrict__ re,
                                             u32* __restrict__ deg){
  int e = blockIdx.x * 256 + threadIdx.x;
  int s = se[e], r = re[e];
  atomicAdd(&deg[s], 1u);
  atomicAdd(&deg[r], 1u);
}

__global__ __launch_bounds__(256) void k_scan1(const u32* __restrict__ deg, u32* __restrict__ bsum){
  __shared__ u32 sh[256];
  int t = threadIdx.x;
  int base = blockIdx.x * 1024 + t * 4;
  u32 s = deg[base] + deg[base+1] + deg[base+2] + deg[base+3];
  sh[t] = s; __syncthreads();
  for (int o = 128; o > 0; o >>= 1){ if (t < o) sh[t] += sh[t+o]; __syncthreads(); }
  if (t == 0) bsum[blockIdx.x] = sh[0];
}

__global__ void k_scan2(u32* __restrict__ bsum){
  __shared__ u32 sh[128];
  int t = threadIdx.x;            // 128 threads
  u32 v = bsum[t];
  sh[t] = v; __syncthreads();
  for (int o = 1; o < 128; o <<= 1){
    u32 x = (t >= o) ? sh[t-o] : 0u;
    __syncthreads();
    sh[t] += x;
    __syncthreads();
  }
  bsum[t] = sh[t] - v;            // exclusive
}

__global__ __launch_bounds__(256) void k_scan3(const u32* __restrict__ bsum,
                                               const u32* __restrict__ deg, u32* __restrict__ off){
  __shared__ u32 sh[256];
  int t = threadIdx.x;
  int base = blockIdx.x * 1024 + t * 4;
  u32 v0 = deg[base], v1 = deg[base+1], v2 = deg[base+2], v3 = deg[base+3];
  u32 s = v0 + v1 + v2 + v3;
  sh[t] = s; __syncthreads();
  for (int o = 1; o < 256; o <<= 1){
    u32 x = (t >= o) ? sh[t-o] : 0u;
    __syncthreads();
    sh[t] += x;
    __syncthreads();
  }
  u32 ex = sh[t] - s + bsum[blockIdx.x];
  off[base]   = ex; ex += v0;
  off[base+1] = ex; ex += v1;
  off[base+2] = ex; ex += v2;
  off[base+3] = ex;
  if (blockIdx.x == 0 && t == 0) off[N_NODES] = 2u * N_EDGES;
}

// gcur[b] = off[b*512] (start of bucket b's region)
__global__ void k_gcinit(const u32* __restrict__ off, u32* __restrict__ gcur){
  int t = threadIdx.x;
  gcur[t] = off[t * 512];
}

// Pass A: bin (target, neighbor) entries into 256 buckets via LDS, flush coalesced
// into pairs[] laid out at CSR bucket offsets. payload = (nlocal[9b] << 17) | nbr[17b]
__global__ __launch_bounds__(256) void k_bin(const int* __restrict__ se, const int* __restrict__ re,
                                             u32* __restrict__ gcur, u32* __restrict__ pairs){
  __shared__ u32 cnt[256], sc[256], base[256], cur[256], gpos[256];
  __shared__ u32 stage[8192];
  int t = threadIdx.x;
  cnt[t] = 0;
  __syncthreads();
  int e0 = blockIdx.x * 4096;
  for (int i = t; i < 4096; i += 256){
    int s = se[e0 + i], r = re[e0 + i];
    atomicAdd(&cnt[(u32)r >> 9], 1u);
    atomicAdd(&cnt[(u32)s >> 9], 1u);
  }
  __syncthreads();
  sc[t] = cnt[t];
  __syncthreads();
  for (int o = 1; o < 256; o <<= 1){
    u32 x = (t >= o) ? sc[t - o] : 0u;
    __syncthreads();
    sc[t] += x;
    __syncthreads();
  }
  base[t] = sc[t] - cnt[t];
  cur[t] = base[t];
  gpos[t] = atomicAdd(&gcur[t], cnt[t]);
  __syncthreads();
  for (int i = t; i < 4096; i += 256){
    u32 s = (u32)se[e0 + i], r = (u32)re[e0 + i];
    u32 b1 = r >> 9, p1 = ((r & 511u) << 17) | s;
    u32 b2 = s >> 9, p2 = ((s & 511u) << 17) | r;
    stage[atomicAdd(&cur[b1], 1u)] = p1;
    stage[atomicAdd(&cur[b2], 1u)] = p2;
  }
  __syncthreads();
  int lane = t & 63, wv = t >> 6;
  for (int b = wv; b < 256; b += 4){
    u32 n = cnt[b], src = base[b], dst = gpos[b];
    for (u32 i = lane; i < n; i += 64)
      pairs[dst + i] = stage[src + i];
  }
}

// Pass B: one block per bucket; place entries into exact CSR slots. adj writes
// stay inside the bucket's ~16KB window -> L2-combined, no line bouncing.
__global__ __launch_bounds__(256) void k_place(const u32* __restrict__ off,
                                               const u32* __restrict__ pairs,
                                               u32* __restrict__ adj){
  __shared__ u32 offl[513];
  __shared__ u32 curl[512];
  int b = blockIdx.x, t = threadIdx.x;
  for (int i = t; i < 513; i += 256) offl[i] = off[b * 512 + i];
  for (int i = t; i < 512; i += 256) curl[i] = 0;
  __syncthreads();
  u32 beg = offl[0], end = offl[512];
  for (u32 i = beg + t; i < end; i += 256){
    u32 p = pairs[i];
    u32 nl = p >> 17, m = p & 0x1FFFFu;
    u32 slot = offl[nl] + atomicAdd(&curl[nl], 1u);
    adj[slot] = m;
  }
}

// ---------------- persistent MFMA GEMM kernels ----------------
// Template: weights staged once into swizzled LDS (one __syncthreads), then a
// barrier-free grid-stride tile loop. A-fragments built in VGPRs straight from
// global; the 16KB repack buffer is wave-private (each wave only touches its own
// 16 rows) so inter-wave sync is never needed; within-wave cross-lane LDS handoffs
// are ordered by the in-order DS pipe + wave_barrier (scheduling fence, 0 cost).
// This removes global loads from the MFMA dependency chain (round-4/5 disease:
// MfmaUtil 4%, latency-bound B loads) and removes vmcnt-draining barriers.

// S[n] = kept[n] ? bf16(x[n]*tval[n] @ dW1) : 0
__global__ __launch_bounds__(256, 3) void k_proj_down(
    const void* __restrict__ xraw, const float* __restrict__ tval,
    const u16* __restrict__ W1T, const SelState* __restrict__ st,
    const u32* __restrict__ kept, u32* __restrict__ S)
{
  __shared__ u16 w1s[128 * 128];   // 32KB swizzled
  __shared__ u16 os[64 * 128];     // 16KB wave-private repack
  int t = threadIdx.x, lane = t & 63, wv = t >> 6;
  int m0 = wv * 16, mn = lane & 15, quad = lane >> 4;

  for (int i = t; i < 2048; i += 256){
    int row = i >> 4, cc = i & 15;
    *(uint4*)&w1s[swz16(row, cc)] = *(const uint4*)(W1T + row * 128 + cc * 8);
  }
  int isf = st->is_f32;
  __syncthreads();

  for (int tile = blockIdx.x; tile < N_TILES; tile += gridDim.x){
    int row0 = tile * 64;
    int arow = row0 + m0 + mn;
    float tv = tval[arow];
    bf8 a[4];
    if (isf){
      const float* xf = (const float*)xraw + (size_t)arow * 128;
      #pragma unroll
      for (int s = 0; s < 4; s++) a[s] = cvt_f32_chunk(xf, s, quad, tv);
    } else {
      const u32* xw = (const u32*)xraw + (size_t)arow * 64;
      #pragma unroll
      for (int s = 0; s < 4; s++) a[s] = scale_bf16_chunk(xw, s, quad, tv);
    }
    f4 acc[8];
    #pragma unroll
    for (int j = 0; j < 8; j++){ acc[j][0]=0.f; acc[j][1]=0.f; acc[j][2]=0.f; acc[j][3]=0.f; }
    gemm_ab(w1s, a, mn, quad, acc);

    #pragma unroll
    for (int j = 0; j < 8; j++){
      int c = j * 16 + mn;
      #pragma unroll
      for (int rg = 0; rg < 4; rg++){
        int row = m0 + quad * 4 + rg;
        os[row * 128 + ((c >> 3) ^ (row & 15)) * 8 + (c & 7)] = (u16)f2bf(acc[j][rg]);
      }
    }
    __builtin_amdgcn_wave_barrier();
    int rl = m0 + (lane >> 2), qt = lane & 3;
    u32 kp = kept[row0 + rl];
    u32* out = S + (size_t)(row0 + rl) * 64;
    #pragma unroll
    for (int i = 0; i < 4; i++){
      int cc = qt * 4 + i;
      uint4 w = *(const uint4*)&os[swz16(rl, cc)];
      if (!kp){ w.x = 0; w.y = 0; w.z = 0; w.w = 0; }
      *(uint4*)(out + cc * 4) = w;
    }
    __builtin_amdgcn_wave_barrier();  // readback before next tile overwrites os
  }
}

// S2[n] = bf16(R[n] @ uW1[0:128,:] + x[n] @ uW1[128:256,:])
__global__ __launch_bounds__(256, 2) void k_proj_up(
    const u32* __restrict__ R, const void* __restrict__ xraw,
    const u16* __restrict__ W1T, const SelState* __restrict__ st,
    u32* __restrict__ S2)
{
  __shared__ u16 was[128 * 128];   // uW1 rows, k 0:128
  __shared__ u16 wbs[128 * 128];   // uW1 rows, k 128:256
  __shared__ u16 os[64 * 128];
  int t = threadIdx.x, lane = t & 63, wv = t >> 6;
  int m0 = wv * 16, mn = lane & 15, quad = lane >> 4;

  for (int i = t; i < 2048; i += 256){
    int row = i >> 4, cc = i & 15;
    *(uint4*)&was[swz16(row, cc)] = *(const uint4*)(W1T + row * 256 + cc * 8);
    *(uint4*)&wbs[swz16(row, cc)] = *(const uint4*)(W1T + row * 256 + 128 + cc * 8);
  }
  int isf = st->is_f32;
  __syncthreads();

  for (int tile = blockIdx.x; tile < N_TILES; tile += gridDim.x){
    int row0 = tile * 64;
    int arow = row0 + m0 + mn;
    bf8 a[4];
    const u32* rp = R + (size_t)arow * 64;
    #pragma unroll
    for (int s = 0; s < 4; s++) a[s] = ld_bf16_chunk(rp, s, quad);
    f4 acc[8];
    #pragma unroll
    for (int j = 0; j < 8; j++){ acc[j][0]=0.f; acc[j][1]=0.f; acc[j][2]=0.f; acc[j][3]=0.f; }
    gemm_ab(was, a, mn, quad, acc);

    if (isf){
      const float* xf = (const float*)xraw + (size_t)arow * 128;
      #pragma unroll
      for (int s = 0; s < 4; s++) a[s] = cvt_f32_chunk(xf, s, quad, 1.0f);
    } else {
      const u32* xw = (const u32*)xraw + (size_t)arow * 64;
      #pragma unroll
      for (int s = 0; s < 4; s++) a[s] = ld_bf16_chunk(xw, s, quad);
    }
    gemm_ab(wbs, a, mn, quad, acc);

    #pragma unroll
    for (int j = 0; j < 8; j++){
      int c = j * 16 + mn;
      #pragma unroll
      for (int rg = 0; rg < 4; rg++){
        int row = m0 + quad * 4 + rg;
        os[row * 128 + ((c >> 3) ^ (row & 15)) * 8 + (c & 7)] = (u16)f2bf(acc[j][rg]);
      }
    }
    __builtin_amdgcn_wave_barrier();
    int rl = m0 + (lane >> 2), qt = lane & 3;
    u32* out = S2 + (size_t)(row0 + rl) * 64;
    #pragma unroll
    for (int i = 0; i < 4; i++){
      int cc = qt * 4 + i;
      *(uint4*)(out + cc * 4) = *(const uint4*)&os[swz16(rl, cc)];
    }
    __builtin_amdgcn_wave_barrier();
  }
}

// ---------------- dedicated high-occupancy pull-aggregation ----------------
template<int IS_DOWN>
__global__ __launch_bounds__(256, 4) void k_agg(
    const u32* __restrict__ Smsg, const u32* __restrict__ off, const u32* __restrict__ adj,
    const u16* __restrict__ cb1, const u32* __restrict__ kept,
    u32* __restrict__ H)
{
  int t = threadIdx.x, lane = t & 63, wv = t >> 6;
  float b1l = bf2f(cb1[2 * lane]), b1h = bf2f(cb1[2 * lane + 1]);
  int base = blockIdx.x * 16 + wv * 4;
  #pragma unroll 1
  for (int rr = 0; rr < 4; rr++){
    int n = base + rr;
    if (IS_DOWN && !kept[n]){ H[(size_t)n * 64 + lane] = 0u; continue; }
    u32 jb = off[n], je = off[n + 1];
    float a0 = 0.f, a1 = 0.f;
    u32 j = jb;
    for (; j + 8 <= je; j += 8){
      u32 e0 = adj[j],   e1 = adj[j+1], e2 = adj[j+2], e3 = adj[j+3];
      u32 e4 = adj[j+4], e5 = adj[j+5], e6 = adj[j+6], e7 = adj[j+7];
      u32 w0 = Smsg[(size_t)e0 * 64 + lane];
      u32 w1 = Smsg[(size_t)e1 * 64 + lane];
      u32 w2 = Smsg[(size_t)e2 * 64 + lane];
      u32 w3 = Smsg[(size_t)e3 * 64 + lane];
      u32 w4 = Smsg[(size_t)e4 * 64 + lane];
      u32 w5 = Smsg[(size_t)e5 * 64 + lane];
      u32 w6 = Smsg[(size_t)e6 * 64 + lane];
      u32 w7 = Smsg[(size_t)e7 * 64 + lane];
      a0 += ((bflo(w0) + bflo(w1)) + (bflo(w2) + bflo(w3)))
          + ((bflo(w4) + bflo(w5)) + (bflo(w6) + bflo(w7)));
      a1 += ((bfhi(w0) + bfhi(w1)) + (bfhi(w2) + bfhi(w3)))
          + ((bfhi(w4) + bfhi(w5)) + (bfhi(w6) + bfhi(w7)));
    }
    for (; j + 4 <= je; j += 4){
      u32 e0 = adj[j], e1 = adj[j+1], e2 = adj[j+2], e3 = adj[j+3];
      u32 w0 = Smsg[(size_t)e0 * 64 + lane];
      u32 w1 = Smsg[(size_t)e1 * 64 + lane];
      u32 w2 = Smsg[(size_t)e2 * 64 + lane];
      u32 w3 = Smsg[(size_t)e3 * 64 + lane];
      a0 += (bflo(w0) + bflo(w1)) + (bflo(w2) + bflo(w3));
      a1 += (bfhi(w0) + bfhi(w1)) + (bfhi(w2) + bfhi(w3));
    }
    for (; j < je; j++){
      u32 w = Smsg[(size_t)adj[j] * 64 + lane];
      a0 += bflo(w); a1 += bfhi(w);
    }
    H[(size_t)n * 64 + lane] = f2bf(gelu_f(a0 + b1l)) | (f2bf(gelu_f(a1 + b1h)) << 16);
  }
}

// ---------------- persistent MFMA MLP tail ----------------
template<int IS_DOWN>
__global__ __launch_bounds__(256, 2) void k_mlp(
    const u32* __restrict__ H,
    const u16* __restrict__ cW2T, const u16* __restrict__ cb2,
    const u16* __restrict__ cW3T, const u16* __restrict__ cb3,
    const u16* __restrict__ cg, const u16* __restrict__ cbe,
    const u32* __restrict__ kept, const SelState* __restrict__ st,
    u32* __restrict__ Rout, void* __restrict__ fout)
{
  __shared__ u16 w2s[128 * 128];
  __shared__ u16 w3s[128 * 128];
  __shared__ u16 os[64 * 128];     // h2 staging, then output repack (wave-private)
  int t = threadIdx.x, lane = t & 63, wv = t >> 6;
  int m0 = wv * 16, mn = lane & 15, quad = lane >> 4;

  for (int i = t; i < 2048; i += 256){
    int row = i >> 4, cc = i & 15;
    *(uint4*)&w2s[swz16(row, cc)] = *(const uint4*)(cW2T + row * 128 + cc * 8);
    *(uint4*)&w3s[swz16(row, cc)] = *(const uint4*)(cW3T + row * 128 + cc * 8);
  }
  // hoist per-lane LN/bias params (cols j*16+mn)
  float b2v[8], b3v[8], gv[8], bev[8];
  #pragma unroll
  for (int j = 0; j < 8; j++){
    int c = j * 16 + mn;
    b2v[j] = bf2f(cb2[c]); b3v[j] = bf2f(cb3[c]);
    gv[j]  = bf2f(cg[c]);  bev[j] = bf2f(cbe[c]);
  }
  int isf = st->is_f32;
  __syncthreads();

  for (int tile = blockIdx.x; tile < N_TILES; tile += gridDim.x){
    int row0 = tile * 64;
    int arow = row0 + m0 + mn;

    // gemm1: A = h1 rows direct from global (gelu already applied in k_agg)
    bf8 a[4];
    const u32* hp = H + (size_t)arow * 64;
    #pragma unroll
    for (int s = 0; s < 4; s++) a[s] = ld_bf16_chunk(hp, s, quad);
    f4 acc[8];
    #pragma unroll
    for (int j = 0; j < 8; j++){ acc[j][0]=0.f; acc[j][1]=0.f; acc[j][2]=0.f; acc[j][3]=0.f; }
    gemm_ab(w2s, a, mn, quad, acc);

    // h2 = gelu(acc + b2) -> os (own rows)
    #pragma unroll
    for (int j = 0; j < 8; j++){
      int c = j * 16 + mn;
      #pragma unroll
      for (int rg = 0; rg < 4; rg++){
        int row = m0 + quad * 4 + rg;
        os[row * 128 + ((c >> 3) ^ (row & 15)) * 8 + (c & 7)] = (u16)f2bf(gelu_f(acc[j][rg] + b2v[j]));
      }
    }
    __builtin_amdgcn_wave_barrier();

    // gemm2: A = h2 from os
    #pragma unroll
    for (int s = 0; s < 4; s++) a[s] = *(const bf8*)&os[swz16(m0 + mn, s * 4 + quad)];
    #pragma unroll
    for (int j = 0; j < 8; j++){ acc[j][0]=0.f; acc[j][1]=0.f; acc[j][2]=0.f; acc[j][3]=0.f; }
    gemm_ab(w3s, a, mn, quad, acc);

    // y = acc + b3, in-register LN (16-lane xor tree within quad group)
    #pragma unroll
    for (int j = 0; j < 8; j++){
      #pragma unroll
      for (int rg = 0; rg < 4; rg++) acc[j][rg] += b3v[j];
    }
    float s1[4] = {0.f,0.f,0.f,0.f}, s2[4] = {0.f,0.f,0.f,0.f};
    #pragma unroll
    for (int j = 0; j < 8; j++){
      #pragma unroll
      for (int rg = 0; rg < 4; rg++){
        float v = acc[j][rg];
        s1[rg] += v; s2[rg] += v * v;
      }
    }
    #pragma unroll
    for (int o = 1; o < 16; o <<= 1){
      #pragma unroll
      for (int rg = 0; rg < 4; rg++){
        s1[rg] += __shfl_xor(s1[rg], o, 64);
        s2[rg] += __shfl_xor(s2[rg], o, 64);
      }
    }
    float mu[4], rs[4];
    #pragma unroll
    for (int rg = 0; rg < 4; rg++){
      mu[rg] = s1[rg] * 0.0078125f;
      float var = s2[rg] * 0.0078125f - mu[rg] * mu[rg];
      rs[rg] = rsqrtf(var + LN_EPS);
    }
    #pragma unroll
    for (int j = 0; j < 8; j++){
      #pragma unroll
      for (int rg = 0; rg < 4; rg++)
        acc[j][rg] = (acc[j][rg] - mu[rg]) * rs[rg] * gv[j] + bev[j];
    }

    if (!IS_DOWN && isf){
      // f32 output: direct stores (16 lanes x 4B = 64B contiguous per (j,rg))
      float* fo = (float*)fout;
      #pragma unroll
      for (int j = 0; j < 8; j++){
        #pragma unroll
        for (int rg = 0; rg < 4; rg++)
          fo[(size_t)(row0 + m0 + quad * 4 + rg) * 128 + j * 16 + mn] = acc[j][rg];
      }
      continue;  // os untouched this tile beyond h2 (reused next tile after gemm2 reads)
    }

    // bf16 output: repack own rows into os (after gemm2 reads), coalesced store
    __builtin_amdgcn_wave_barrier();
    #pragma unroll
    for (int j = 0; j < 8; j++){
      int c = j * 16 + mn;
      #pragma unroll
      for (int rg = 0; rg < 4; rg++){
        int row = m0 + quad * 4 + rg;
        os[row * 128 + ((c >> 3) ^ (row & 15)) * 8 + (c & 7)] = (u16)f2bf(acc[j][rg]);
      }
    }
    __builtin_amdgcn_wave_barrier();
    int rl = m0 + (lane >> 2), qt = lane & 3;
    u32 kp = IS_DOWN ? kept[row0 + rl] : 1u;
    u32* out = (IS_DOWN ? Rout : (u32*)fout) + (size_t)(row0 + rl) * 64;
    #pragma unroll
    for (int i = 0; i < 4; i++){
      int cc = qt * 4 + i;
      uint4 w = *(const uint4*)&os[swz16(rl, cc)];
      if (!kp){ w.x = 0; w.y = 0; w.z = 0; w.w = 0; }
      *(uint4*)(out + cc * 4) = w;
    }
    __builtin_amdgcn_wave_barrier();
  }
}

// ---------------- host launch ----------------

extern "C" void kernel_launch(void* const* d_in, const int* in_sizes, int n_in,
                              void* d_out, int out_size, void* d_ws, size_t ws_size,
                              hipStream_t stream)
{
  const void* x     = d_in[0];
  const int* eidx   = (const int*)d_in[1];
  const void* poolp = d_in[2];
  const int* senders = eidx;
  const int* receivers = eidx + N_EDGES;

  char* ws = (char*)d_ws;
  SelState* st = (SelState*)(ws + ST_OFF);
  u16*  canon  = (u16*) (ws + CANON_OFF);
  u32*  partial= (u32*) (ws + PART_OFF);   // radix partials; bsum overlays
  u64*  keys   = (u64*) (ws + KEYS_OFF);
  float* tval  = (float*)(ws + TVAL_OFF);
  u32*  kept   = (u32*) (ws + KEPT_OFF);
  u32*  Sbuf   = (u32*) (ws + SBUF_OFF);   // 32MB ws big-buffer (pairs, then messages)
  u32*  off    = (u32*) (ws + OFF_OFF);
  u32*  adj    = (u32*) (ws + ADJ_OFF);
  u32*  deg    = (u32*) (ws + KEYS_OFF);   // deg overlays keys (dead after k_mark)
  u32*  bsum   = partial;
  u32*  gcur   = partial + 512;            // 256 u32 bucket cursors
  u32*  pairs  = Sbuf;                     // 4MB staging (consumed before proj)
  u32*  Dbuf   = (u32*) d_out;             // 32MB d_out scratch region

  P16 ps;
  for (int i = 0; i < 16; i++) ps.q[i] = d_in[3 + i];

  k_detect<<<1, 256, 0, stream>>>((const u32*)x, st);
  k_init<<<1, 64, 0, stream>>>(st);
  k_canon<<<(C_TOT + 255) / 256, 256, 0, stream>>>(ps, st, canon);
  k_canon_t<<<(T_REGION + 255) / 256, 256, 0, stream>>>(canon);
  k_pnorm<<<1, 128, 0, stream>>>(poolp, st);
  k_score<<<N_NODES / 4, 256, 0, stream>>>(x, poolp, st, keys, tval);
  for (int pass = 0; pass < 4; pass++){
    k_histp<<<256, 256, 0, stream>>>(keys, st, partial, pass);
    k_scanp<<<1, 256, 0, stream>>>(partial, st);
  }
  k_mark<<<N_NODES / 256, 256, 0, stream>>>(keys, st, kept);
  k_tie<<<1, 256, 0, stream>>>(st, kept);

  // ---- CSR build (keys region is dead now): deg -> scan -> bucketed 2-pass fill ----
  hipMemsetAsync(deg, 0, (size_t)N_NODES * 4, stream);
  k_deg<<<N_EDGES / 256, 256, 0, stream>>>(senders, receivers, deg);
  k_scan1<<<128, 256, 0, stream>>>(deg, bsum);
  k_scan2<<<1, 128, 0, stream>>>(bsum);
  k_scan3<<<128, 256, 0, stream>>>(bsum, deg, off);
  k_gcinit<<<1, 256, 0, stream>>>(off, gcur);
  k_bin<<<N_EDGES / 4096, 256, 0, stream>>>(senders, receivers, gcur, pairs);
  k_place<<<256, 256, 0, stream>>>(off, pairs, adj);

  // ---- down conv: S(ws) -> agg H(d_out) -> MLP -> R(ws) ----
  k_proj_down<<<768, 256, 0, stream>>>(x, tval, canon + CT_DW1, st, kept, Sbuf);
  k_agg<1><<<N_NODES / 16, 256, 0, stream>>>(Sbuf, off, adj, canon + C_DB1, kept, Dbuf);
  k_mlp<1><<<512, 256, 0, stream>>>(Dbuf,
      canon + CT_DW2, canon + C_DB2, canon + CT_DW3, canon + C_DB3,
      canon + C_DG, canon + C_DBE, kept, st, Sbuf, nullptr);

  // ---- up conv: R(ws) -> S2(d_out) -> agg H(ws) -> MLP -> d_out ----
  k_proj_up<<<512, 256, 0, stream>>>(Sbuf, x, canon + CT_UW1, st, Dbuf);
  k_agg<0><<<N_NODES / 16, 256, 0, stream>>>(Dbuf, off, adj, canon + C_UB1, kept, Sbuf);
  k_mlp<0><<<512, 256, 0, stream>>>(Sbuf,
      canon + CT_UW2, canon + C_UB2, canon + CT_UW3, canon + C_UB3,
      canon + C_UG, canon + C_UBE, kept, st, nullptr, d_out);
}